// Round 13
// baseline (338.433 us; speedup 1.0000x reference)
//
#include <hip/hip_runtime.h>
#include <math.h>

#define DD 128

typedef __attribute__((ext_vector_type(8))) short short8;
typedef __attribute__((ext_vector_type(4))) float f32x4;

__device__ __forceinline__ unsigned short f2b(float f) {
    unsigned int x = __float_as_uint(f);
    return (unsigned short)((x + 0x7FFFu + ((x >> 16) & 1u)) >> 16);   // RNE bf16
}
__device__ __forceinline__ float b2f(unsigned short u) {
    return __uint_as_float(((unsigned int)u) << 16);
}

// ---------------- fused setup: blocks [0,192) transpose W->bf16, rest histogram dst ----------------
__global__ __launch_bounds__(256) void k_setup(const int* __restrict__ dst, int* __restrict__ cnt, int E,
                                               const float* __restrict__ W0, const float* __restrict__ W1,
                                               const float* __restrict__ W2, unsigned short* __restrict__ T0,
                                               unsigned short* __restrict__ T1, unsigned short* __restrict__ T2) {
    int bid = blockIdx.x;
    if (bid < 192) {
        int l = bid >> 6;
        const float* W = (l == 0) ? W0 : (l == 1) ? W1 : W2;
        unsigned short* WT = (l == 0) ? T0 : (l == 1) ? T1 : T2;
        int idx = (bid & 63) * 256 + threadIdx.x;   // 16384
        int k = idx >> 7, c = idx & 127;
        WT[c * DD + k] = f2b(W[idx]);
    } else {
        int e = (bid - 192) * 256 + threadIdx.x;
        if (e < E) atomicAdd(&cnt[dst[e]], 1);
    }
}

// ---------------- hierarchical scan ----------------
__global__ __launch_bounds__(256) void k_scan1(const int* __restrict__ cnt, int* __restrict__ part, int N) {
    __shared__ int lds[256];
    int t = threadIdx.x;
    int i = blockIdx.x * 256 + t;
    lds[t] = (i < N) ? cnt[i] : 0;
    __syncthreads();
#pragma unroll
    for (int off = 128; off > 0; off >>= 1) {
        if (t < off) lds[t] += lds[t + off];
        __syncthreads();
    }
    if (t == 0) part[blockIdx.x] = lds[0];
}

__global__ __launch_bounds__(1024) void k_scan2(int* __restrict__ part, int* __restrict__ rowptr,
                                                int nblk, int N) {
    __shared__ int lds[1024];
    int t = threadIdx.x;
    int v = (t < nblk) ? part[t] : 0;
    lds[t] = v;
    __syncthreads();
    for (int off = 1; off < 1024; off <<= 1) {
        int u = (t >= off) ? lds[t - off] : 0;
        __syncthreads();
        lds[t] += u;
        __syncthreads();
    }
    if (t < nblk) part[t] = lds[t] - v;
    if (t == 1023) rowptr[N] = lds[1023];
}

// scan3 + dinv fused
__global__ __launch_bounds__(256) void k_scan3(const int* __restrict__ cnt, const int* __restrict__ part,
                                               int* __restrict__ rowptr, float* __restrict__ dinv, int N) {
    __shared__ int lds[256];
    int t = threadIdx.x;
    int i = blockIdx.x * 256 + t;
    int v = (i < N) ? cnt[i] : 0;
    lds[t] = v;
    __syncthreads();
    for (int off = 1; off < 256; off <<= 1) {
        int u = (t >= off) ? lds[t - off] : 0;
        __syncthreads();
        lds[t] += u;
        __syncthreads();
    }
    if (i < N) {
        rowptr[i] = part[blockIdx.x] + lds[t] - v;
        dinv[i] = rsqrtf((float)v + 1.0f);
    }
}

// ---------------- pass 1: bin edges into bucket regions of the CSR (bucket = 32 dsts) ----------------
// Appends within a bucket are contiguous -> full-line writes (fixes k_fill's 8x write amplification).
__global__ __launch_bounds__(256) void k_bin(const int* __restrict__ src, const int* __restrict__ dst,
                                             const int* __restrict__ rowptr, int* __restrict__ bcur,
                                             int2* __restrict__ tmp, int E) {
    int e = blockIdx.x * 256 + threadIdx.x;
    if (e >= E) return;
    int s = src[e], d = dst[e];
    int b = d >> 5;
    int base = rowptr[b << 5];
    int slot = atomicAdd(&bcur[b], 1);
    tmp[base + slot] = make_int2(s, d);
}

// ---------------- pass 2: exact placement within bucket (LDS cursors; writes stay L2-local) ----------------
__global__ __launch_bounds__(256) void k_place(const int* __restrict__ rowptr, const int2* __restrict__ tmp,
                                               int* __restrict__ adjS, int N) {
    int b = blockIdx.x;
    int d0 = b << 5;
    int dend = min(d0 + 32, N);
    int base = rowptr[d0], endp = rowptr[dend];
    __shared__ int lcur[32];
    if (threadIdx.x < 32) lcur[threadIdx.x] = 0;
    __syncthreads();
    for (int i = base + threadIdx.x; i < endp; i += 256) {
        int2 sd = tmp[i];
        int pos = atomicAdd(&lcur[sd.y - d0], 1);
        adjS[rowptr[sd.y] + pos] = sd.x;
    }
}

// ---------------- MFMA GEMM: HS_bf16[N,128] = dinv[r] * (X[N,128] @ W), 128-row tile ----------------
template <int IN_BF16>
__global__ __launch_bounds__(256) void k_gemm_mfma(const void* __restrict__ Xv,
                                                   const unsigned short* __restrict__ WT,
                                                   const float* __restrict__ dinv,
                                                   unsigned short* __restrict__ H, int N) {
    __shared__ __align__(16) unsigned short sB[DD * DD];    // 32 KB swizzled
    __shared__ __align__(16) unsigned short sA[DD * DD];    // 32 KB swizzled
    int tid = threadIdx.x;
    long row0 = (long)blockIdx.x * 128;

#pragma unroll
    for (int i = 0; i < 8; ++i) {
        int q = tid + 256 * i;
        int c = q >> 4, j = q & 15;
        short8 v = *(const short8*)(WT + q * 8);
        int byte = c * 256 + ((j * 16) ^ ((c & 7) << 4));
        *(short8*)((char*)sB + byte) = v;
    }
#pragma unroll
    for (int i = 0; i < 8; ++i) {
        int q = tid + 256 * i;
        int r = q >> 4, j = q & 15;
        short8 v;
        if (IN_BF16) {
#pragma unroll
            for (int z = 0; z < 8; ++z) v[z] = 0;
            if (row0 + r < N) v = *(const short8*)((const unsigned short*)Xv + (row0 + r) * DD + j * 8);
        } else {
            float4 a0 = make_float4(0.f, 0.f, 0.f, 0.f), a1 = a0;
            if (row0 + r < N) {
                const float4* p = (const float4*)((const float*)Xv + (row0 + r) * DD + j * 8);
                a0 = p[0];
                a1 = p[1];
            }
            v[0] = (short)f2b(a0.x); v[1] = (short)f2b(a0.y);
            v[2] = (short)f2b(a0.z); v[3] = (short)f2b(a0.w);
            v[4] = (short)f2b(a1.x); v[5] = (short)f2b(a1.y);
            v[6] = (short)f2b(a1.z); v[7] = (short)f2b(a1.w);
        }
        int byte = r * 256 + ((j * 16) ^ ((r & 7) << 4));
        *(short8*)((char*)sA + byte) = v;
    }
    __syncthreads();

    int w = tid >> 6, l = tid & 63;
    int lr = l & 15, kg = l >> 4;
    int ar0 = w * 32 + lr, ar1 = w * 32 + 16 + lr;
    f32x4 acc0[8] = {}, acc1[8] = {};

#pragma unroll
    for (int step = 0; step < 4; ++step) {
        int koff = step * 64 + kg * 16;
        short8 a0 = *(const short8*)((const char*)sA + ar0 * 256 + (koff ^ ((ar0 & 7) << 4)));
        short8 a1 = *(const short8*)((const char*)sA + ar1 * 256 + (koff ^ ((ar1 & 7) << 4)));
#pragma unroll
        for (int ct = 0; ct < 8; ++ct) {
            int c = ct * 16 + lr;
            short8 bf = *(const short8*)((const char*)sB + c * 256 + (koff ^ ((c & 7) << 4)));
            acc0[ct] = __builtin_amdgcn_mfma_f32_16x16x32_bf16(a0, bf, acc0[ct], 0, 0, 0);
            acc1[ct] = __builtin_amdgcn_mfma_f32_16x16x32_bf16(a1, bf, acc1[ct], 0, 0, 0);
        }
    }

    // dinv prescale: HS[r] = dinv[r] * h[r]  (single bf16 rounding)
    float dv0[4], dv1[4];
#pragma unroll
    for (int reg = 0; reg < 4; ++reg) {
        long r = row0 + w * 32 + kg * 4 + reg;
        dv0[reg] = (r < N) ? dinv[r] : 0.f;
        dv1[reg] = (r + 16 < N) ? dinv[r + 16] : 0.f;
    }
    // C/D: col = l&15, row = (l>>4)*4 + reg (per 16-row strip)
#pragma unroll
    for (int ct = 0; ct < 8; ++ct) {
#pragma unroll
        for (int reg = 0; reg < 4; ++reg) {
            long r = row0 + w * 32 + kg * 4 + reg;
            if (r < N) H[r * DD + ct * 16 + lr] = f2b(dv0[reg] * acc0[ct][reg]);
            long r2 = r + 16;
            if (r2 < N) H[r2 * DD + ct * 16 + lr] = f2b(dv1[reg] * acc1[ct][reg]);
        }
    }
}

// ------- fused: aggregate (hs bf16, weightless adj) -> LN -> residual -> SiLU -> x_out bf16 -------
// out = b + dinv[row]*(hs[row] + sum_nbrs hs[s]). Pad edges (s=0) masked by wave-uniform 0/1.
template <int IN_BF16>
__global__ __launch_bounds__(256) void k_agg(const unsigned short* __restrict__ h, const void* __restrict__ xin,
                                             const int* __restrict__ rowptr, const int* __restrict__ adjS,
                                             const float* __restrict__ dinv, const float* __restrict__ b,
                                             const float* __restrict__ g, const float* __restrict__ be,
                                             unsigned int* __restrict__ xout, int N) {
    int row = blockIdx.x * 4 + (threadIdx.x >> 6);
    if (row >= N) return;
    int lane = threadIdx.x & 63;
    const unsigned int* hu = (const unsigned int*)h;

    float dv = dinv[row];
    unsigned int us = hu[(size_t)row * 64 + lane];
    float selfx = b2f((unsigned short)(us & 0xFFFF));
    float selfy = b2f((unsigned short)(us >> 16));
    float2 acc = make_float2(0.f, 0.f);

    int beg = rowptr[row], end = rowptr[row + 1];
    for (int j0 = beg; j0 < end; j0 += 64) {
        int myj = j0 + lane;
        int a = (myj < end) ? adjS[myj] : 0;
        int cnt = min(64, end - j0);
        int cntR = (cnt + 15) & ~15;
        for (int k0 = 0; k0 < cntR; k0 += 16) {
            unsigned int un[16];
#pragma unroll
            for (int u = 0; u < 16; ++u) {
                int s = __shfl(a, k0 + u, 64);
                un[u] = hu[(size_t)s * 64 + lane];
            }
#pragma unroll
            for (int u = 0; u < 16; ++u) {
                float m = (k0 + u < cnt) ? 1.0f : 0.0f;   // wave-uniform mask
                acc.x = fmaf(m, b2f((unsigned short)(un[u] & 0xFFFF)), acc.x);
                acc.y = fmaf(m, b2f((unsigned short)(un[u] >> 16)), acc.y);
            }
        }
    }

    float2 bv = ((const float2*)b)[lane];
    float ox = fmaf(dv, selfx + acc.x, bv.x);
    float oy = fmaf(dv, selfy + acc.y, bv.y);

    // LayerNorm over 128
    float ssum = ox + oy;
#pragma unroll
    for (int o = 32; o > 0; o >>= 1) ssum += __shfl_xor(ssum, o, 64);
    float mu = ssum * (1.0f / 128.0f);
    float dx0 = ox - mu, dx1 = oy - mu;
    float vs = dx0 * dx0 + dx1 * dx1;
#pragma unroll
    for (int o = 32; o > 0; o >>= 1) vs += __shfl_xor(vs, o, 64);
    float rstd = rsqrtf(vs * (1.0f / 128.0f) + 1e-5f);

    float2 gv = ((const float2*)g)[lane];
    float2 bev = ((const float2*)be)[lane];
    float2 xv;
    if (IN_BF16) {
        unsigned int xu = ((const unsigned int*)xin)[(size_t)row * 64 + lane];
        xv = make_float2(b2f((unsigned short)(xu & 0xFFFF)), b2f((unsigned short)(xu >> 16)));
    } else {
        xv = ((const float2*)xin)[(size_t)row * 64 + lane];
    }
    float a0 = fmaf(dx0 * rstd, gv.x, bev.x) + xv.x;
    float a1 = fmaf(dx1 * rstd, gv.y, bev.y) + xv.y;
    a0 = a0 / (1.0f + expf(-a0));
    a1 = a1 / (1.0f + expf(-a1));
    xout[(size_t)row * 64 + lane] = ((unsigned int)f2b(a1) << 16) | (unsigned int)f2b(a0);
}

// ------- pool: one block per graph (batch sorted -> contiguous ranges), x bf16 -------
__global__ __launch_bounds__(256) void k_pool2(const unsigned int* __restrict__ x, const int* __restrict__ batch,
                                               float* __restrict__ out, int N) {
    int gi = blockIdx.x;
    int lo = 0, hi = N;
    while (lo < hi) { int m = (lo + hi) >> 1; if (batch[m] < gi) lo = m + 1; else hi = m; }
    int beg = lo;
    lo = beg; hi = N;
    while (lo < hi) { int m = (lo + hi) >> 1; if (batch[m] < gi + 1) lo = m + 1; else hi = m; }
    int end = lo;

    int tid = threadIdx.x;
    int wave = tid >> 6, lane = tid & 63;
    float2 acc = make_float2(0.f, 0.f);
    for (int r = beg + wave; r < end; r += 4) {
        unsigned int u = x[(size_t)r * 64 + lane];
        acc.x += b2f((unsigned short)(u & 0xFFFF));
        acc.y += b2f((unsigned short)(u >> 16));
    }
    __shared__ float part[4][DD];
    ((float2*)part[wave])[lane] = acc;
    __syncthreads();
    if (wave == 0) {
        float sx = 0.f, sy = 0.f;
#pragma unroll
        for (int w = 0; w < 4; ++w) {
            float2 v = ((const float2*)part[w])[lane];
            sx += v.x;
            sy += v.y;
        }
        float inv = 1.0f / fmaxf((float)(end - beg), 1.0f);
        ((float2*)(out + (size_t)gi * DD))[lane] = make_float2(sx * inv, sy * inv);
    }
}

extern "C" void kernel_launch(void* const* d_in, const int* in_sizes, int n_in,
                              void* d_out, int out_size, void* d_ws, size_t ws_size,
                              hipStream_t stream) {
    const float* x = (const float*)d_in[0];
    const int* edge = (const int*)d_in[1];
    const int* batch = (const int*)d_in[2];
    const float* W[3] = {(const float*)d_in[3], (const float*)d_in[7], (const float*)d_in[11]};
    const float* b[3] = {(const float*)d_in[4], (const float*)d_in[8], (const float*)d_in[12]};
    const float* g[3] = {(const float*)d_in[5], (const float*)d_in[9], (const float*)d_in[13]};
    const float* be[3] = {(const float*)d_in[6], (const float*)d_in[10], (const float*)d_in[14]};

    int N = in_sizes[0] / DD;
    int E = in_sizes[1] / 2;
    int G = out_size / DD;
    const int* srcI = edge;
    const int* dstI = edge + E;

    int nblk = (N + 255) / 256;
    int nbuck = (N + 31) / 32;

    char* ws = (char*)d_ws;
    size_t ND = (size_t)N * DD;
    unsigned int* bufX = (unsigned int*)ws;           ws += ND * 2;   // x state, bf16
    unsigned short* bufH = (unsigned short*)ws;       ws += ND * 2;   // hs = dinv*h, bf16
    unsigned short* wt[3];
    for (int l = 0; l < 3; ++l) { wt[l] = (unsigned short*)ws; ws += (size_t)DD * DD * 2; }
    float* dinv = (float*)ws;                         ws += (size_t)N * 4;
    int* cnt = (int*)ws;                              ws += (size_t)N * 4;
    int* bcur = (int*)ws;                             ws += (size_t)nbuck * 4;
    int* rowptr = (int*)ws;                           ws += (size_t)(N + 1) * 4;
    int* part = (int*)ws;                             ws += (size_t)nblk * 4;
    ws = (char*)(((uintptr_t)ws + 15) & ~(uintptr_t)15);
    int2* tmp = (int2*)ws;                            ws += (size_t)E * 8;
    int* adjS = (int*)ws;

    hipMemsetAsync(cnt, 0, ((size_t)N + nbuck) * 4, stream);   // cnt + bcur adjacent

    k_setup<<<192 + (E + 255) / 256, 256, 0, stream>>>(dstI, cnt, E, W[0], W[1], W[2], wt[0], wt[1], wt[2]);
    k_scan1<<<nblk, 256, 0, stream>>>(cnt, part, N);
    k_scan2<<<1, 1024, 0, stream>>>(part, rowptr, nblk, N);
    k_scan3<<<nblk, 256, 0, stream>>>(cnt, part, rowptr, dinv, N);
    k_bin<<<(E + 255) / 256, 256, 0, stream>>>(srcI, dstI, rowptr, bcur, tmp, E);
    k_place<<<nbuck, 256, 0, stream>>>(rowptr, tmp, adjS, N);

    int gblk = (N + 127) / 128, ablk = (N + 3) / 4;
    // layer 0: fp32 input
    k_gemm_mfma<0><<<gblk, 256, 0, stream>>>(x, wt[0], dinv, bufH, N);
    k_agg<0><<<ablk, 256, 0, stream>>>(bufH, x, rowptr, adjS, dinv, b[0], g[0], be[0], bufX, N);
    // layers 1,2: bf16 state (in-place safe: each thread reads own row before writing)
    for (int l = 1; l < 3; ++l) {
        k_gemm_mfma<1><<<gblk, 256, 0, stream>>>(bufX, wt[l], dinv, bufH, N);
        k_agg<1><<<ablk, 256, 0, stream>>>(bufH, bufX, rowptr, adjS, dinv, b[l], g[l], be[l], bufX, N);
    }

    k_pool2<<<G, 256, 0, stream>>>(bufX, batch, (float*)d_out, N);
}

// Round 14
// 257.008 us; speedup vs baseline: 1.3168x; 1.3168x over previous
//
#include <hip/hip_runtime.h>
#include <math.h>

#define DD 128

typedef __attribute__((ext_vector_type(8))) short short8;
typedef __attribute__((ext_vector_type(4))) float f32x4;

__device__ __forceinline__ unsigned short f2b(float f) {
    unsigned int x = __float_as_uint(f);
    return (unsigned short)((x + 0x7FFFu + ((x >> 16) & 1u)) >> 16);   // RNE bf16
}
__device__ __forceinline__ float b2f(unsigned short u) {
    return __uint_as_float(((unsigned int)u) << 16);
}

// ---------------- fused setup: blocks [0,192) transpose W->bf16, rest histogram dst ----------------
__global__ __launch_bounds__(256) void k_setup(const int* __restrict__ dst, int* __restrict__ cnt, int E,
                                               const float* __restrict__ W0, const float* __restrict__ W1,
                                               const float* __restrict__ W2, unsigned short* __restrict__ T0,
                                               unsigned short* __restrict__ T1, unsigned short* __restrict__ T2) {
    int bid = blockIdx.x;
    if (bid < 192) {
        int l = bid >> 6;
        const float* W = (l == 0) ? W0 : (l == 1) ? W1 : W2;
        unsigned short* WT = (l == 0) ? T0 : (l == 1) ? T1 : T2;
        int idx = (bid & 63) * 256 + threadIdx.x;   // 16384
        int k = idx >> 7, c = idx & 127;
        WT[c * DD + k] = f2b(W[idx]);
    } else {
        int e = (bid - 192) * 256 + threadIdx.x;
        if (e < E) atomicAdd(&cnt[dst[e]], 1);
    }
}

// ---------------- hierarchical scan ----------------
__global__ __launch_bounds__(256) void k_scan1(const int* __restrict__ cnt, int* __restrict__ part, int N) {
    __shared__ int lds[256];
    int t = threadIdx.x;
    int i = blockIdx.x * 256 + t;
    lds[t] = (i < N) ? cnt[i] : 0;
    __syncthreads();
#pragma unroll
    for (int off = 128; off > 0; off >>= 1) {
        if (t < off) lds[t] += lds[t + off];
        __syncthreads();
    }
    if (t == 0) part[blockIdx.x] = lds[0];
}

__global__ __launch_bounds__(1024) void k_scan2(int* __restrict__ part, int* __restrict__ rowptr,
                                                int nblk, int N) {
    __shared__ int lds[1024];
    int t = threadIdx.x;
    int v = (t < nblk) ? part[t] : 0;
    lds[t] = v;
    __syncthreads();
    for (int off = 1; off < 1024; off <<= 1) {
        int u = (t >= off) ? lds[t - off] : 0;
        __syncthreads();
        lds[t] += u;
        __syncthreads();
    }
    if (t < nblk) part[t] = lds[t] - v;
    if (t == 1023) rowptr[N] = lds[1023];
}

// scan3 + dinv fused
__global__ __launch_bounds__(256) void k_scan3(const int* __restrict__ cnt, const int* __restrict__ part,
                                               int* __restrict__ rowptr, float* __restrict__ dinv, int N) {
    __shared__ int lds[256];
    int t = threadIdx.x;
    int i = blockIdx.x * 256 + t;
    int v = (i < N) ? cnt[i] : 0;
    lds[t] = v;
    __syncthreads();
    for (int off = 1; off < 256; off <<= 1) {
        int u = (t >= off) ? lds[t - off] : 0;
        __syncthreads();
        lds[t] += u;
        __syncthreads();
    }
    if (i < N) {
        rowptr[i] = part[blockIdx.x] + lds[t] - v;
        dinv[i] = rsqrtf((float)v + 1.0f);
    }
}

// ---------------- fill adjacency (single pass, src-only 4B payload) ----------------
// 12 contenders/cursor address = low atomic serialization (round-13 lesson: bucketed
// counters at 384 contenders/address serialized to 110us).
__global__ __launch_bounds__(256) void k_fill(const int* __restrict__ src, const int* __restrict__ dst,
                                              const int* __restrict__ rowptr, int* __restrict__ cursor,
                                              int* __restrict__ adjS, int E) {
    int e = blockIdx.x * 256 + threadIdx.x;
    if (e >= E) return;
    int s = src[e], d = dst[e];
    int pos = atomicAdd(&cursor[d], 1);
    adjS[rowptr[d] + pos] = s;
}

// ---------------- MFMA GEMM: HS_bf16[N,128] = dinv[r] * (X[N,128] @ W), 128-row tile ----------------
template <int IN_BF16>
__global__ __launch_bounds__(256) void k_gemm_mfma(const void* __restrict__ Xv,
                                                   const unsigned short* __restrict__ WT,
                                                   const float* __restrict__ dinv,
                                                   unsigned short* __restrict__ H, int N) {
    __shared__ __align__(16) unsigned short sB[DD * DD];    // 32 KB swizzled
    __shared__ __align__(16) unsigned short sA[DD * DD];    // 32 KB swizzled
    int tid = threadIdx.x;
    long row0 = (long)blockIdx.x * 128;

#pragma unroll
    for (int i = 0; i < 8; ++i) {
        int q = tid + 256 * i;
        int c = q >> 4, j = q & 15;
        short8 v = *(const short8*)(WT + q * 8);
        int byte = c * 256 + ((j * 16) ^ ((c & 7) << 4));
        *(short8*)((char*)sB + byte) = v;
    }
#pragma unroll
    for (int i = 0; i < 8; ++i) {
        int q = tid + 256 * i;
        int r = q >> 4, j = q & 15;
        short8 v;
        if (IN_BF16) {
#pragma unroll
            for (int z = 0; z < 8; ++z) v[z] = 0;
            if (row0 + r < N) v = *(const short8*)((const unsigned short*)Xv + (row0 + r) * DD + j * 8);
        } else {
            float4 a0 = make_float4(0.f, 0.f, 0.f, 0.f), a1 = a0;
            if (row0 + r < N) {
                const float4* p = (const float4*)((const float*)Xv + (row0 + r) * DD + j * 8);
                a0 = p[0];
                a1 = p[1];
            }
            v[0] = (short)f2b(a0.x); v[1] = (short)f2b(a0.y);
            v[2] = (short)f2b(a0.z); v[3] = (short)f2b(a0.w);
            v[4] = (short)f2b(a1.x); v[5] = (short)f2b(a1.y);
            v[6] = (short)f2b(a1.z); v[7] = (short)f2b(a1.w);
        }
        int byte = r * 256 + ((j * 16) ^ ((r & 7) << 4));
        *(short8*)((char*)sA + byte) = v;
    }
    __syncthreads();

    int w = tid >> 6, l = tid & 63;
    int lr = l & 15, kg = l >> 4;
    int ar0 = w * 32 + lr, ar1 = w * 32 + 16 + lr;
    f32x4 acc0[8] = {}, acc1[8] = {};

#pragma unroll
    for (int step = 0; step < 4; ++step) {
        int koff = step * 64 + kg * 16;
        short8 a0 = *(const short8*)((const char*)sA + ar0 * 256 + (koff ^ ((ar0 & 7) << 4)));
        short8 a1 = *(const short8*)((const char*)sA + ar1 * 256 + (koff ^ ((ar1 & 7) << 4)));
#pragma unroll
        for (int ct = 0; ct < 8; ++ct) {
            int c = ct * 16 + lr;
            short8 bf = *(const short8*)((const char*)sB + c * 256 + (koff ^ ((c & 7) << 4)));
            acc0[ct] = __builtin_amdgcn_mfma_f32_16x16x32_bf16(a0, bf, acc0[ct], 0, 0, 0);
            acc1[ct] = __builtin_amdgcn_mfma_f32_16x16x32_bf16(a1, bf, acc1[ct], 0, 0, 0);
        }
    }

    // dinv prescale: HS[r] = dinv[r] * h[r]
    float dv0[4], dv1[4];
#pragma unroll
    for (int reg = 0; reg < 4; ++reg) {
        long r = row0 + w * 32 + kg * 4 + reg;
        dv0[reg] = (r < N) ? dinv[r] : 0.f;
        dv1[reg] = (r + 16 < N) ? dinv[r + 16] : 0.f;
    }
#pragma unroll
    for (int ct = 0; ct < 8; ++ct) {
#pragma unroll
        for (int reg = 0; reg < 4; ++reg) {
            long r = row0 + w * 32 + kg * 4 + reg;
            if (r < N) H[r * DD + ct * 16 + lr] = f2b(dv0[reg] * acc0[ct][reg]);
            long r2 = r + 16;
            if (r2 < N) H[r2 * DD + ct * 16 + lr] = f2b(dv1[reg] * acc1[ct][reg]);
        }
    }
}

// ------- fused: aggregate (hs bf16, weightless adj) -> LN -> residual -> SiLU -> x_out bf16 -------
template <int IN_BF16>
__global__ __launch_bounds__(256) void k_agg(const unsigned short* __restrict__ h, const void* __restrict__ xin,
                                             const int* __restrict__ rowptr, const int* __restrict__ adjS,
                                             const float* __restrict__ dinv, const float* __restrict__ b,
                                             const float* __restrict__ g, const float* __restrict__ be,
                                             unsigned int* __restrict__ xout, int N) {
    int row = blockIdx.x * 4 + (threadIdx.x >> 6);
    if (row >= N) return;
    int lane = threadIdx.x & 63;
    const unsigned int* hu = (const unsigned int*)h;

    float dv = dinv[row];
    unsigned int us = hu[(size_t)row * 64 + lane];
    float selfx = b2f((unsigned short)(us & 0xFFFF));
    float selfy = b2f((unsigned short)(us >> 16));
    float2 acc = make_float2(0.f, 0.f);

    int beg = rowptr[row], end = rowptr[row + 1];
    for (int j0 = beg; j0 < end; j0 += 64) {
        int myj = j0 + lane;
        int a = (myj < end) ? adjS[myj] : 0;
        int cnt = min(64, end - j0);
        int cntR = (cnt + 15) & ~15;
        for (int k0 = 0; k0 < cntR; k0 += 16) {
            unsigned int un[16];
#pragma unroll
            for (int u = 0; u < 16; ++u) {
                int s = __shfl(a, k0 + u, 64);
                un[u] = hu[(size_t)s * 64 + lane];
            }
#pragma unroll
            for (int u = 0; u < 16; ++u) {
                float m = (k0 + u < cnt) ? 1.0f : 0.0f;   // wave-uniform mask
                acc.x = fmaf(m, b2f((unsigned short)(un[u] & 0xFFFF)), acc.x);
                acc.y = fmaf(m, b2f((unsigned short)(un[u] >> 16)), acc.y);
            }
        }
    }

    float2 bv = ((const float2*)b)[lane];
    float ox = fmaf(dv, selfx + acc.x, bv.x);
    float oy = fmaf(dv, selfy + acc.y, bv.y);

    // LayerNorm over 128
    float ssum = ox + oy;
#pragma unroll
    for (int o = 32; o > 0; o >>= 1) ssum += __shfl_xor(ssum, o, 64);
    float mu = ssum * (1.0f / 128.0f);
    float dx0 = ox - mu, dx1 = oy - mu;
    float vs = dx0 * dx0 + dx1 * dx1;
#pragma unroll
    for (int o = 32; o > 0; o >>= 1) vs += __shfl_xor(vs, o, 64);
    float rstd = rsqrtf(vs * (1.0f / 128.0f) + 1e-5f);

    float2 gv = ((const float2*)g)[lane];
    float2 bev = ((const float2*)be)[lane];
    float2 xv;
    if (IN_BF16) {
        unsigned int xu = ((const unsigned int*)xin)[(size_t)row * 64 + lane];
        xv = make_float2(b2f((unsigned short)(xu & 0xFFFF)), b2f((unsigned short)(xu >> 16)));
    } else {
        xv = ((const float2*)xin)[(size_t)row * 64 + lane];
    }
    float a0 = fmaf(dx0 * rstd, gv.x, bev.x) + xv.x;
    float a1 = fmaf(dx1 * rstd, gv.y, bev.y) + xv.y;
    a0 = a0 / (1.0f + expf(-a0));
    a1 = a1 / (1.0f + expf(-a1));
    xout[(size_t)row * 64 + lane] = ((unsigned int)f2b(a1) << 16) | (unsigned int)f2b(a0);
}

// ------- pool: one block per graph (batch sorted -> contiguous ranges), x bf16 -------
__global__ __launch_bounds__(256) void k_pool2(const unsigned int* __restrict__ x, const int* __restrict__ batch,
                                               float* __restrict__ out, int N) {
    int gi = blockIdx.x;
    int lo = 0, hi = N;
    while (lo < hi) { int m = (lo + hi) >> 1; if (batch[m] < gi) lo = m + 1; else hi = m; }
    int beg = lo;
    lo = beg; hi = N;
    while (lo < hi) { int m = (lo + hi) >> 1; if (batch[m] < gi + 1) lo = m + 1; else hi = m; }
    int end = lo;

    int tid = threadIdx.x;
    int wave = tid >> 6, lane = tid & 63;
    float2 acc = make_float2(0.f, 0.f);
    for (int r = beg + wave; r < end; r += 4) {
        unsigned int u = x[(size_t)r * 64 + lane];
        acc.x += b2f((unsigned short)(u & 0xFFFF));
        acc.y += b2f((unsigned short)(u >> 16));
    }
    __shared__ float part[4][DD];
    ((float2*)part[wave])[lane] = acc;
    __syncthreads();
    if (wave == 0) {
        float sx = 0.f, sy = 0.f;
#pragma unroll
        for (int w = 0; w < 4; ++w) {
            float2 v = ((const float2*)part[w])[lane];
            sx += v.x;
            sy += v.y;
        }
        float inv = 1.0f / fmaxf((float)(end - beg), 1.0f);
        ((float2*)(out + (size_t)gi * DD))[lane] = make_float2(sx * inv, sy * inv);
    }
}

extern "C" void kernel_launch(void* const* d_in, const int* in_sizes, int n_in,
                              void* d_out, int out_size, void* d_ws, size_t ws_size,
                              hipStream_t stream) {
    const float* x = (const float*)d_in[0];
    const int* edge = (const int*)d_in[1];
    const int* batch = (const int*)d_in[2];
    const float* W[3] = {(const float*)d_in[3], (const float*)d_in[7], (const float*)d_in[11]};
    const float* b[3] = {(const float*)d_in[4], (const float*)d_in[8], (const float*)d_in[12]};
    const float* g[3] = {(const float*)d_in[5], (const float*)d_in[9], (const float*)d_in[13]};
    const float* be[3] = {(const float*)d_in[6], (const float*)d_in[10], (const float*)d_in[14]};

    int N = in_sizes[0] / DD;
    int E = in_sizes[1] / 2;
    int G = out_size / DD;
    const int* srcI = edge;
    const int* dstI = edge + E;

    int nblk = (N + 255) / 256;

    char* ws = (char*)d_ws;
    size_t ND = (size_t)N * DD;
    unsigned int* bufX = (unsigned int*)ws;           ws += ND * 2;   // x state, bf16
    unsigned short* bufH = (unsigned short*)ws;       ws += ND * 2;   // hs = dinv*h, bf16
    unsigned short* wt[3];
    for (int l = 0; l < 3; ++l) { wt[l] = (unsigned short*)ws; ws += (size_t)DD * DD * 2; }
    float* dinv = (float*)ws;                         ws += (size_t)N * 4;
    int* cnt = (int*)ws;                              ws += (size_t)N * 4;
    int* cursor = (int*)ws;                           ws += (size_t)N * 4;
    int* rowptr = (int*)ws;                           ws += (size_t)(N + 1) * 4;
    int* part = (int*)ws;                             ws += (size_t)nblk * 4;
    int* adjS = (int*)ws;

    hipMemsetAsync(cnt, 0, (size_t)N * 2 * 4, stream);   // cnt + cursor adjacent

    k_setup<<<192 + (E + 255) / 256, 256, 0, stream>>>(dstI, cnt, E, W[0], W[1], W[2], wt[0], wt[1], wt[2]);
    k_scan1<<<nblk, 256, 0, stream>>>(cnt, part, N);
    k_scan2<<<1, 1024, 0, stream>>>(part, rowptr, nblk, N);
    k_scan3<<<nblk, 256, 0, stream>>>(cnt, part, rowptr, dinv, N);
    k_fill<<<(E + 255) / 256, 256, 0, stream>>>(srcI, dstI, rowptr, cursor, adjS, E);

    int gblk = (N + 127) / 128, ablk = (N + 3) / 4;
    // layer 0: fp32 input
    k_gemm_mfma<0><<<gblk, 256, 0, stream>>>(x, wt[0], dinv, bufH, N);
    k_agg<0><<<ablk, 256, 0, stream>>>(bufH, x, rowptr, adjS, dinv, b[0], g[0], be[0], bufX, N);
    // layers 1,2: bf16 state (in-place safe: each thread reads own row before writing)
    for (int l = 1; l < 3; ++l) {
        k_gemm_mfma<1><<<gblk, 256, 0, stream>>>(bufX, wt[l], dinv, bufH, N);
        k_agg<1><<<ablk, 256, 0, stream>>>(bufH, bufX, rowptr, adjS, dinv, b[l], g[l], be[l], bufX, N);
    }

    k_pool2<<<G, 256, 0, stream>>>(bufX, batch, (float*)d_out, N);
}